// Round 5
// baseline (301.151 us; speedup 1.0000x reference)
//
#include <hip/hip_runtime.h>
#include <math.h>

#define BB 128
#define DD 256
#define SS 512
#define KK 50
#define HH 256
#define TS 128               // s-tile
#define NTILES (BB * SS / TS) // 512
#define NBLK (NTILES * 2)    // 1024 (x2 k-halves)
#define BS (BB * SS)         // 65536

#define CHUNK 1024
#define NCH (BS / CHUNK)     // 64
#define NCHBLK (KK * NCH / 4) // 800 chunk blocks
#define TOPK 32
#define MAXSURV 512
#define NSUB (TS / 16)       // 8 survivor subtiles per tile

// workspace layout (float offsets)
#define TVN_OFF 0
#define TVNT_OFF (TVN_OFF + DD * KK)          // 12800
#define TPNT_OFF (TVNT_OFF + KK * DD)         // 25600
#define PREDACC_OFF (TPNT_OFF + KK * BS)
#define AE_OFF (PREDACC_OFF + BB * DD)        // +32768
#define SIM_OFF (AE_OFF + 1)
#define CNT_OFF (AE_OFF + 2)                  // surv_cnt
#define SIMD_OFF (AE_OFF + 3)                 // sim_done counter
#define TFLAG_OFF (AE_OFF + 4)                // NTILES ints
#define TCNT_OFF (TFLAG_OFF + NTILES)         // NTILES ints
#define KDONE_OFF (TCNT_OFF + NTILES)         // KK ints (per-concept chunk counters)
#define SDONE_OFF (KDONE_OFF + KK)            // 1 int (survivor-block counter)
#define NZERO (BB * DD + 4 + 2 * NTILES + KK + 1)  // contiguous zero region from PREDACC
#define LIST_OFF (SDONE_OFF + 1)              // MAXSURV ints (no zeroing needed)
#define CAND_OFF (LIST_OFF + MAXSURV)         // KK*NCH*TOPK floats

// out layout: pred[0:256), 0.0@256, sim@257, far@258, nn[259:259+3276800), ae@3277059
#define OUT_NN_OFF 259
#define OUT_AE_IDX (OUT_NN_OFF + KK * BS)

__device__ __forceinline__ unsigned fkey(float f) {
  unsigned u = __float_as_uint(f);
  return (u & 0x80000000u) ? ~u : (u | 0x80000000u);
}
__device__ __forceinline__ float keyval(unsigned T) {
  unsigned u = (T & 0x80000000u) ? (T & 0x7FFFFFFFu) : ~T;
  return __uint_as_float(u);
}

// tvn + transposed copy; also zeroes predacc/scalars/tile flags/kdone/sdone
__global__ __launch_bounds__(256) void tvn_kernel(const float* __restrict__ tv,
                                                  float* __restrict__ tvn,
                                                  float* __restrict__ tvnT,
                                                  float* __restrict__ zbase) {
  __shared__ float red[256];
  const int k = blockIdx.x, t = threadIdx.x;
  {
    const int gid = k * 256 + t;                 // 12800 threads total
    for (int i = gid; i < NZERO; i += KK * 256) zbase[i] = 0.0f;
  }
  float v = tv[t * KK + k];
  red[t] = v * v;
  __syncthreads();
  for (int off = 128; off > 0; off >>= 1) {
    if (t < off) red[t] += red[t + off];
    __syncthreads();
  }
  float inv = 1.0f / fmaxf(sqrtf(red[0]), 1e-12f);
  const float nv = v * inv;
  tvn[t * KK + k] = nv;
  tvnT[k * DD + t] = nv;
}

// blk = tile*2 + half. Wave owns k = kb + 8j (kb = half*4+wid, j<7); thread = s-pair (float2).
// x: coalesced dwordx2 + depth-8 prefetch double buffer. tvn: wave-uniform s_load.
// EXACT R2 body (65.5 us verified). Tile epilogue via tile_cnt second-finisher.
__global__ __launch_bounds__(256, 4) void main_kernel(
    const float* __restrict__ f_input, const float* __restrict__ tvnT,
    float* __restrict__ out_nn, float* __restrict__ tpn_t,
    float* __restrict__ ae_acc, int* __restrict__ surv_cnt,
    int* __restrict__ surv_list, int* __restrict__ tile_flag,
    int* __restrict__ tile_cnt) {
  __shared__ int wflag[4];
  __shared__ int decision;   // 1 = zero-fill tile, 0 = nothing

  const int blk = blockIdx.x;
  const int tile = blk >> 1;
  const int half = blk & 1;
  const int b = tile >> 2;
  const int s0 = (tile & 3) * TS;
  const int t = threadIdx.x;
  const int lane = t & 63;
  const int wid = t >> 6;
  const int kb = __builtin_amdgcn_readfirstlane(half * 4 + wid);  // 0..7, wave-uniform

  const float* tvk[7];
  bool kval[7];
  #pragma unroll
  for (int j = 0; j < 7; ++j) {
    const int k = kb + 8 * j;
    kval[j] = (k < KK);
    tvk[j] = tvnT + (size_t)(kval[j] ? k : (KK - 1)) * DD;
  }

  const float* xp = f_input + (size_t)b * DD * SS + s0 + 2 * lane;

  float acc0[7], acc1[7];
  #pragma unroll
  for (int j = 0; j < 7; ++j) { acc0[j] = 0.0f; acc1[j] = 0.0f; }

  // depth-8 prefetch double buffer, 8 d's per group
  float2 xb[2][8];
  #pragma unroll
  for (int i = 0; i < 8; ++i) xb[0][i] = *(const float2*)(xp + (size_t)i * SS);

  float s2_0 = 0.0f, s2_1 = 0.0f;
  int buf = 0;
  for (int part = 0; part < 8; ++part) {
    float p0 = 0.0f, p1 = 0.0f;
    #pragma unroll
    for (int dd = 0; dd < 32; dd += 8) {
      const int d0 = part * 32 + dd;
      const int dn = (d0 + 8 < DD) ? (d0 + 8) : 0;  // clamp: harmless redundant prefetch
      #pragma unroll
      for (int i = 0; i < 8; ++i) xb[buf ^ 1][i] = *(const float2*)(xp + (size_t)(dn + i) * SS);
      #pragma unroll
      for (int g = 0; g < 2; ++g) {
        const float2 xa = xb[buf][4 * g + 0], xc2 = xb[buf][4 * g + 1],
                     xc3 = xb[buf][4 * g + 2], xc4 = xb[buf][4 * g + 3];
        // bit-exact chains: d-ascending per (k,s); norm singleton adds asc
        p0 += xa.x * xa.x; p0 += xc2.x * xc2.x; p0 += xc3.x * xc3.x; p0 += xc4.x * xc4.x;
        p1 += xa.y * xa.y; p1 += xc2.y * xc2.y; p1 += xc3.y * xc3.y; p1 += xc4.y * xc4.y;
        #pragma unroll
        for (int j = 0; j < 7; ++j) {
          const float4 tq = *(const float4*)(tvk[j] + d0 + 4 * g);  // wave-uniform -> s_load
          acc0[j] += xa.x * tq.x; acc0[j] += xc2.x * tq.y;
          acc0[j] += xc3.x * tq.z; acc0[j] += xc4.x * tq.w;
          acc1[j] += xa.y * tq.x; acc1[j] += xc2.y * tq.y;
          acc1[j] += xc3.y * tq.z; acc1[j] += xc4.y * tq.w;
        }
      }
      buf ^= 1;
    }
    s2_0 = (part == 0) ? p0 : (s2_0 + p0);
    s2_1 = (part == 0) ? p1 : (s2_1 + p1);
  }
  const float i0 = 1.0f / fmaxf(sqrtf(s2_0), 1e-12f);
  const float i1 = 1.0f / fmaxf(sqrtf(s2_1), 1e-12f);

  bool m = false;
  const size_t gs = (size_t)b * SS + s0 + 2 * lane;
  #pragma unroll
  for (int j = 0; j < 7; ++j) {
    if (kval[j]) {
      const int k = kb + 8 * j;
      float2 o;
      o.x = acc0[j] * i0;
      o.y = acc1[j] * i1;
      *(float2*)(tpn_t + (size_t)k * BS + gs) = o;
      m = m | (o.x > 0.3f) | (o.y > 0.3f);
    }
  }

  const int w = __any((int)m);
  if (lane == 0) wflag[wid] = w;
  __syncthreads();
  const int blockAny = wflag[0] | wflag[1] | wflag[2] | wflag[3];

  if (t == 0) {
    const int old = atomicOr(&tile_flag[tile], blockAny);
    const int done = atomicAdd(&tile_cnt[tile], 1);
    int dec = 0;
    if (done == 1) {               // second finisher: union is complete
      const int fl = old | blockAny;
      if (fl) {
        const int idx = atomicAdd(surv_cnt, 1);
        if (idx < MAXSURV) surv_list[idx] = tile;
      } else {
        atomicAdd(ae_acc, (float)TS);  // sum_s ||x_n||^2 = TS exactly
        dec = 1;
      }
    }
    decision = dec;
  }
  __syncthreads();
  if (decision) {
    float* ob = out_nn + ((size_t)b * SS + s0) * KK;
    for (int p2 = t; p2 < TS * KK; p2 += 256) ob[p2] = 0.0f;
  }
}

// Fused: blocks [0,800) = per-wave exact top-32 of 1024-elem chunks, with
//   per-concept 16th-finisher running the top-32 MERGE for that concept
//   (feeds sim_acc/sim_done; 50th sim finisher writes out[257]).
// blocks [800,864) = survivor tiles; the 64th sdone-finisher runs the pred
//   head + concept_far + ae/out[256] epilogue (predacc complete by then).
// All finisher hand-offs: writer fence -> atomic signal; winner fence -> read.
__global__ __launch_bounds__(256) void chunk_surv_kernel(
    const float* __restrict__ tpn_t, float* __restrict__ cand,
    const float* __restrict__ f_input, const float* __restrict__ rec1,
    const float* __restrict__ rec2, const int* __restrict__ surv_cnt,
    const int* __restrict__ surv_list, float* __restrict__ out_nn,
    float* __restrict__ predacc, float* __restrict__ ae_acc,
    int* __restrict__ kdone, int* __restrict__ sdone,
    float* __restrict__ sim_acc, unsigned* __restrict__ sim_done,
    const float* __restrict__ tvn, const float* __restrict__ Wc,
    const float* __restrict__ bc, float* __restrict__ out) {
  __shared__ __align__(16) float NNk[KK * 20];   // [k][s16] stride 20
  __shared__ __align__(16) float R1t[HH * 20];   // [h][s16] stride 20
  __shared__ float nprt[16][17];
  __shared__ float nrm[16], invn[16];
  __shared__ float pm[8 * DD];
  __shared__ float red4[4];
  __shared__ int doFin;

  const int t = threadIdx.x;
  const int lane = t & 63, wid = t >> 6;

  if (blockIdx.x < NCHBLK) {
    // ---------- chunk top-32 path (no LDS, no barriers in hot part) ----------
    const int gchunk = blockIdx.x * 4 + wid;
    const int k = gchunk >> 6;
    const int c = gchunk & (NCH - 1);
    const float* row = tpn_t + (size_t)k * BS + c * CHUNK;

    float v[16];
    unsigned key[16];
    #pragma unroll
    for (int j = 0; j < 16; ++j) {
      v[j] = row[lane + j * 64];
      key[j] = fkey(v[j]);
    }
    unsigned T = 0;
    for (int bit = 31; bit >= 0; --bit) {
      const unsigned ct = T | (1u << bit);
      int cnt = 0;
      #pragma unroll
      for (int j = 0; j < 16; ++j) cnt += (key[j] >= ct) ? 1 : 0;
      #pragma unroll
      for (int off = 1; off < 64; off <<= 1) cnt += __shfl_xor(cnt, off);
      if (cnt >= TOPK) T = ct;
    }
    int cg = 0;
    #pragma unroll
    for (int j = 0; j < 16; ++j) cg += (key[j] > T) ? 1 : 0;
    int incl = cg;
    #pragma unroll
    for (int off = 1; off < 64; off <<= 1) {
      int y = __shfl_up(incl, off);
      if (lane >= off) incl += y;
    }
    const int excl = incl - cg;
    const int total_gt = __shfl(incl, 63);

    float* cb = cand + (size_t)gchunk * TOPK;
    int pos = excl;
    #pragma unroll
    for (int j = 0; j < 16; ++j) {
      if (key[j] > T) cb[pos++] = v[j];
    }
    if (lane < TOPK - total_gt) cb[total_gt + lane] = keyval(T);

    // ---- per-concept finisher: 16 blocks/concept; 16th runs the merge ----
    const int kc = blockIdx.x >> 4;   // concept of all 4 chunks in this block
    __syncthreads();
    __threadfence();                  // release cand writes (all waves)
    if (t == 0) {
      const int old = atomicAdd(&kdone[kc], 1);
      doFin = (old == 15);
    }
    __syncthreads();
    if (doFin) {
      __threadfence();                // acquire other blocks' cand writes
      if (t < 64) {
        const float* mrow = cand + (size_t)kc * (NCH * TOPK);
        float mv[32];
        unsigned mkey[32];
        #pragma unroll
        for (int j = 0; j < 32; ++j) {
          mv[j] = mrow[t + j * 64];
          mkey[j] = fkey(mv[j]);
        }
        unsigned MT = 0;
        for (int bit = 31; bit >= 0; --bit) {
          const unsigned ct = MT | (1u << bit);
          int cnt = 0;
          #pragma unroll
          for (int j = 0; j < 32; ++j) cnt += (mkey[j] >= ct) ? 1 : 0;
          #pragma unroll
          for (int off = 1; off < 64; off <<= 1) cnt += __shfl_xor(cnt, off);
          if (cnt >= TOPK) MT = ct;
        }
        float s = 0.0f;
        int cgt = 0;
        #pragma unroll
        for (int j = 0; j < 32; ++j) {
          if (mkey[j] > MT) { s += mv[j]; cgt++; }
        }
        #pragma unroll
        for (int off = 1; off < 64; off <<= 1) {
          s += __shfl_xor(s, off);
          cgt += __shfl_xor(cgt, off);
        }
        if (t == 0) {
          atomicAdd(sim_acc, s + (float)(TOPK - cgt) * keyval(MT));
          __threadfence();
          const unsigned c2 = atomicAdd(sim_done, 1u);
          if (c2 == KK - 1) {           // last finisher: total is complete
            __threadfence();
            const float tot = atomicAdd(sim_acc, 0.0f);
            out[257] = -tot * (1.0f / (float)(KK * TOPK));
          }
        }
      }
    }
    return;
  }

  // ---------- survivor path ----------
  const int bid = blockIdx.x - NCHBLK;   // 0..63
  int cnt = *surv_cnt;
  if (cnt > MAXSURV) cnt = MAXSURV;
  const int ntask = NSUB * cnt;

  for (int task = bid; task < ntask; task += 64) {
    const int tile = surv_list[task / NSUB];
    const int q = task % NSUB;
    const int b = tile >> 2;
    const int s0 = (tile & 3) * TS + q * 16;
    const float* fb = f_input + (size_t)b * DD * SS;
    const size_t gs0 = (size_t)b * SS + s0;

    // stage tpn rows for these 16 s
    for (int p = t; p < KK * 16; p += 256) {
      const int k = p >> 4, ss = p & 15;
      NNk[k * 20 + ss] = tpn_t[(size_t)k * BS + gs0 + ss];
    }
    // cooperative norms: 16 d-parts x 16 s
    {
      const int ss = t & 15, part = t >> 4;
      const float* xc = fb + (size_t)(part * 16) * SS + s0 + ss;
      float p = 0.0f;
      #pragma unroll
      for (int i = 0; i < 16; ++i) {
        const float v = xc[(size_t)i * SS];
        p += v * v;
      }
      nprt[part][ss] = p;
    }
    __syncthreads();
    if (t < 16) {
      float s2 = 0.0f;
      #pragma unroll
      for (int i = 0; i < 16; ++i) s2 += nprt[i][t];
      const float n = fmaxf(sqrtf(s2), 1e-12f);
      nrm[t] = n;
      invn[t] = 1.0f / n;
      float sm = 0.0f;
      for (int k = 0; k < KK; ++k) {
        const float tpn = NNk[k * 20 + t];
        sm += (tpn > 0.3f) ? tpn * n : 0.0f;
      }
      const float idv = 1.0f / (sm + 0.001f + 1e-8f);
      for (int k = 0; k < KK; ++k) {
        const float tpn = NNk[k * 20 + t];
        NNk[k * 20 + t] = (tpn > 0.3f) ? tpn * n * idv : 0.0f;
      }
    }
    __syncthreads();

    // write out_nn for these 16 s (scalar: out_nn only 4B-aligned)
    for (int p = t; p < 16 * KK; p += 256) {
      const int ss = p / KK, k = p - ss * KK;
      out_nn[(gs0 + ss) * KK + k] = NNk[k * 20 + ss];
    }

    // phase 4: r1[h=t][s] = relu(nn . rec1)
    {
      float a[16];
      #pragma unroll
      for (int i = 0; i < 16; ++i) a[i] = 0.0f;
      #pragma unroll 2
      for (int k = 0; k < KK; ++k) {
        const float r = rec1[k * HH + t];
        const float4* np = (const float4*)&NNk[k * 20];
        #pragma unroll
        for (int qq = 0; qq < 4; ++qq) {
          const float4 nv = np[qq];
          a[qq * 4 + 0] += nv.x * r;
          a[qq * 4 + 1] += nv.y * r;
          a[qq * 4 + 2] += nv.z * r;
          a[qq * 4 + 3] += nv.w * r;
        }
      }
      #pragma unroll
      for (int i = 0; i < 16; ++i) R1t[t * 20 + i] = fmaxf(a[i], 0.0f);
    }
    __syncthreads();

    // phase 5: r2 = r1 @ rec2; per thread 2s x 8d
    const int tx = t & 31, ty = t >> 5;
    const int d0 = tx * 8, sb = ty * 2;
    float c2[2][8];
    #pragma unroll
    for (int i = 0; i < 2; ++i)
      #pragma unroll
      for (int j = 0; j < 8; ++j) c2[i][j] = 0.0f;
    for (int h0 = 0; h0 < HH; h0 += 8) {
      float4 B0[8], B1[8];
      #pragma unroll
      for (int u = 0; u < 8; ++u) {
        B0[u] = *(const float4*)(rec2 + (h0 + u) * DD + d0);
        B1[u] = *(const float4*)(rec2 + (h0 + u) * DD + d0 + 4);
      }
      #pragma unroll
      for (int u = 0; u < 8; ++u) {
        const float2 a01 = *(const float2*)(&R1t[(h0 + u) * 20 + sb]);
        const float bv[8] = {B0[u].x, B0[u].y, B0[u].z, B0[u].w,
                             B1[u].x, B1[u].y, B1[u].z, B1[u].w};
        #pragma unroll
        for (int j = 0; j < 8; ++j) {
          c2[0][j] += a01.x * bv[j];
          c2[1][j] += a01.y * bv[j];
        }
      }
    }
    #pragma unroll
    for (int j = 0; j < 8; ++j) pm[ty * DD + d0 + j] = c2[0][j] + c2[1][j];
    __syncthreads();
    {
      float sum = 0.0f;
      #pragma unroll
      for (int r = 0; r < 8; ++r) sum += pm[r * DD + t];
      atomicAdd(&predacc[(size_t)b * DD + t], sum);
    }
    float e = 0.0f;
    #pragma unroll
    for (int j = 0; j < 8; ++j) {
      #pragma unroll
      for (int i = 0; i < 2; ++i) {
        const float x = fb[(size_t)(d0 + j) * SS + s0 + sb + i];
        const float diff = x * invn[sb + i] - c2[i][j];
        e += diff * diff;
      }
    }
    #pragma unroll
    for (int off = 1; off < 64; off <<= 1) e += __shfl_xor(e, off);
    if (lane == 0) red4[wid] = e;
    __syncthreads();
    if (t == 0) atomicAdd(ae_acc, red4[0] + red4[1] + red4[2] + red4[3]);
    __syncthreads();  // LDS reuse next task
  }

  // ---- 64th survivor-block finisher: pred head + concept_far + scalars ----
  __syncthreads();
  __threadfence();                    // release predacc/ae atomics (ordering)
  if (t == 0) {
    const int old = atomicAdd(sdone, 1);
    doFin = (old == 63);
  }
  __syncthreads();
  if (!doFin) return;
  __threadfence();                    // acquire all surv blocks' writes

  // pred head: 4 waves x 32 b; replicates old 256-leaf LDS tree BITWISE.
  // Lane l holds leaves t = l, l+64, l+128, l+192:
  //   level-128 pairs (l,l+128),(l+64,l+192) and level-64 are lane-local,
  //   levels 32..1 are shfl_down — identical combine order to the LDS tree.
  // contract(off) keeps the mul/add split matching the old store-then-add form.
  {
    float2 wv[4];
    #pragma unroll
    for (int i = 0; i < 4; ++i) wv[i] = *(const float2*)&Wc[(lane + 64 * i) * 2];
    const float bc0 = bc[0], bc1 = bc[1];
    for (int i = 0; i < 32; ++i) {
      const int b = wid * 32 + i;
      const float* pa = predacc + (size_t)b * DD;
      const float sv0 = pa[lane], sv1 = pa[lane + 64],
                  sv2 = pa[lane + 128], sv3 = pa[lane + 192];
      float a0, a1;
      {
#pragma clang fp contract(off)
        const float m00 = sv0 * wv[0].x, m10 = sv1 * wv[1].x,
                    m20 = sv2 * wv[2].x, m30 = sv3 * wv[3].x;
        const float m01 = sv0 * wv[0].y, m11 = sv1 * wv[1].y,
                    m21 = sv2 * wv[2].y, m31 = sv3 * wv[3].y;
        a0 = (m00 + m20) + (m10 + m30);   // level128 pairs, then level64
        a1 = (m01 + m21) + (m11 + m31);
      }
      #pragma unroll
      for (int off = 32; off > 0; off >>= 1) {
        a0 += __shfl_down(a0, off);
        a1 += __shfl_down(a1, off);
      }
      if (lane == 0) {
        out[b * 2 + 0] = a0 * (1.0f / (float)SS) + bc0;
        out[b * 2 + 1] = a1 * (1.0f / (float)SS) + bc1;
      }
    }
  }
  __syncthreads();

  // concept_far: sum(G) = sum_d (rowsum_d)^2 (verbatim old tree, pm as red)
  {
    float rs = 0.0f;
    for (int k = 0; k < KK; ++k) rs += tvn[t * KK + k];
    pm[t] = rs * rs;
    __syncthreads();
    for (int off = 128; off > 0; off >>= 1) {
      if (t < off) pm[t] += pm[t + off];
      __syncthreads();
    }
    if (t == 0) {
      out[258] = (pm[0] - (float)KK) / ((float)KK * (float)KK);
      out[256] = 0.0f;
      const float ae = atomicAdd(ae_acc, 0.0f);
      out[OUT_AE_IDX] = ae * (1.0f / ((float)BB * (float)SS * (float)DD));
    }
  }
}

extern "C" void kernel_launch(void* const* d_in, const int* in_sizes, int n_in,
                              void* d_out, int out_size, void* d_ws, size_t ws_size,
                              hipStream_t stream) {
  (void)in_sizes; (void)n_in; (void)out_size; (void)ws_size;
  const float* f_input = (const float*)d_in[0];
  const float* tv = (const float*)d_in[2];
  const float* rec1 = (const float*)d_in[3];
  const float* rec2 = (const float*)d_in[4];
  const float* Wc = (const float*)d_in[5];
  const float* bc = (const float*)d_in[6];

  float* out = (float*)d_out;
  float* ws = (float*)d_ws;
  float* tvn = ws + TVN_OFF;
  float* tvnT = ws + TVNT_OFF;
  float* tpn_t = ws + TPNT_OFF;
  float* predacc = ws + PREDACC_OFF;
  float* ae_acc = ws + AE_OFF;
  float* sim_acc = ws + SIM_OFF;
  int* surv_cnt = (int*)(ws + CNT_OFF);
  unsigned* sim_done = (unsigned*)(ws + SIMD_OFF);
  int* tile_flag = (int*)(ws + TFLAG_OFF);
  int* tile_cnt = (int*)(ws + TCNT_OFF);
  int* kdone = (int*)(ws + KDONE_OFF);
  int* sdone = (int*)(ws + SDONE_OFF);
  int* surv_list = (int*)(ws + LIST_OFF);
  float* cand = ws + CAND_OFF;

  tvn_kernel<<<KK, 256, 0, stream>>>(tv, tvn, tvnT, predacc);
  main_kernel<<<NBLK, 256, 0, stream>>>(f_input, tvnT, out + OUT_NN_OFF, tpn_t,
                                        ae_acc, surv_cnt, surv_list,
                                        tile_flag, tile_cnt);
  chunk_surv_kernel<<<NCHBLK + 64, 256, 0, stream>>>(
      tpn_t, cand, f_input, rec1, rec2, surv_cnt, surv_list,
      out + OUT_NN_OFF, predacc, ae_acc, kdone, sdone, sim_acc, sim_done,
      tvn, Wc, bc, out);
}

// Round 6
// 269.505 us; speedup vs baseline: 1.1174x; 1.1174x over previous
//
#include <hip/hip_runtime.h>
#include <math.h>

#define BB 128
#define DD 256
#define SS 512
#define KK 50
#define HH 256
#define TS 128               // s-tile
#define NTILES (BB * SS / TS) // 512
#define NBLK (NTILES * 2)    // 1024 (x2 k-halves)
#define BS (BB * SS)         // 65536

#define CHUNK 1024
#define NCH (BS / CHUNK)     // 64
#define NCHBLK (KK * NCH / 4) // 800 chunk blocks
#define TOPK 32
#define MAXSURV 512
#define NSUB (TS / 16)       // 8 survivor subtiles per tile

// workspace layout (float offsets)
#define TVN_OFF 0
#define TVNT_OFF (TVN_OFF + DD * KK)          // 12800
#define TPNT_OFF (TVNT_OFF + KK * DD)         // 25600
#define PREDACC_OFF (TPNT_OFF + KK * BS)
#define AE_OFF (PREDACC_OFF + BB * DD)        // +32768
#define SIM_OFF (AE_OFF + 1)
#define CNT_OFF (AE_OFF + 2)                  // surv_cnt
#define SIMD_OFF (AE_OFF + 3)                 // sim_done counter
#define TFLAG_OFF (AE_OFF + 4)                // NTILES ints
#define TCNT_OFF (TFLAG_OFF + NTILES)         // NTILES ints
#define NZERO (BB * DD + 4 + 2 * NTILES)      // contiguous zero region from PREDACC
#define LIST_OFF (TCNT_OFF + NTILES)          // MAXSURV ints (no zeroing needed)
#define CAND_OFF (LIST_OFF + MAXSURV)         // KK*NCH*TOPK floats

// out layout: pred[0:256), 0.0@256, sim@257, far@258, nn[259:259+3276800), ae@3277059
#define OUT_NN_OFF 259
#define OUT_AE_IDX (OUT_NN_OFF + KK * BS)

__device__ __forceinline__ unsigned fkey(float f) {
  unsigned u = __float_as_uint(f);
  return (u & 0x80000000u) ? ~u : (u | 0x80000000u);
}
__device__ __forceinline__ float keyval(unsigned T) {
  unsigned u = (T & 0x80000000u) ? (T & 0x7FFFFFFFu) : ~T;
  return __uint_as_float(u);
}

// tvn + transposed copy; also zeroes predacc/scalars/tile flags (replaces memset)
__global__ __launch_bounds__(256) void tvn_kernel(const float* __restrict__ tv,
                                                  float* __restrict__ tvn,
                                                  float* __restrict__ tvnT,
                                                  float* __restrict__ zbase) {
  __shared__ float red[256];
  const int k = blockIdx.x, t = threadIdx.x;
  {
    const int gid = k * 256 + t;                 // 12800 threads total
    for (int i = gid; i < NZERO; i += KK * 256) zbase[i] = 0.0f;
  }
  float v = tv[t * KK + k];
  red[t] = v * v;
  __syncthreads();
  for (int off = 128; off > 0; off >>= 1) {
    if (t < off) red[t] += red[t + off];
    __syncthreads();
  }
  float inv = 1.0f / fmaxf(sqrtf(red[0]), 1e-12f);
  const float nv = v * inv;
  tvn[t * KK + k] = nv;
  tvnT[k * DD + t] = nv;
}

// blk = tile*2 + half. Wave owns k = kb + 8j (kb = half*4+wid, j<7); thread = s-pair (float2).
// x: coalesced dwordx2 + depth-8 prefetch double buffer (verified R2 path).
// tq: NEW — block stages its 28 tvnT rows (28 KB) into LDS once (coalesced
//   float4, one barrier), inner loop reads wave-uniform ds_read_b128 at
//   immediate offsets (same-address broadcast, conflict-free). Rationale:
//   the s_load path serialized on lgkmcnt — 7 s_load_dwordx4 per dd-group at
//   ~200cy scalar-cache-thrash latency vs ~128cy of FMA -> the measured 47%
//   VALU idle; SGPR_Count=112 (at cap) blocked deeper SMEM pipelining.
//   LDS is a bit-copy; FMA order unchanged -> bitwise-identical output.
// Tile epilogue via tile_cnt second-finisher.
__global__ __launch_bounds__(256, 4) void main_kernel(
    const float* __restrict__ f_input, const float* __restrict__ tvnT,
    float* __restrict__ out_nn, float* __restrict__ tpn_t,
    float* __restrict__ ae_acc, int* __restrict__ surv_cnt,
    int* __restrict__ surv_list, int* __restrict__ tile_flag,
    int* __restrict__ tile_cnt) {
  __shared__ __align__(16) float tvs[28 * 256];   // 28 KB: 7 rows per wave
  __shared__ int wflag[4];
  __shared__ int decision;   // 1 = zero-fill tile, 0 = nothing

  const int blk = blockIdx.x;
  const int tile = blk >> 1;
  const int half = blk & 1;
  const int b = tile >> 2;
  const int s0 = (tile & 3) * TS;
  const int t = threadIdx.x;
  const int lane = t & 63;
  const int wid = t >> 6;
  const int kb = __builtin_amdgcn_readfirstlane(half * 4 + wid);  // 0..7, wave-uniform

  bool kval[7];
  {
    // stage this wave's 7 tvnT rows into LDS (coalesced: 64 lanes x 16B = 1KB/row)
    #pragma unroll
    for (int j = 0; j < 7; ++j) {
      const int k = kb + 8 * j;
      kval[j] = (k < KK);
      const float* rowp = tvnT + (size_t)(kval[j] ? k : (KK - 1)) * DD;
      const float4 v4 = *(const float4*)(rowp + 4 * lane);
      *(float4*)&tvs[(wid * 7 + j) * 256 + 4 * lane] = v4;
    }
  }
  __syncthreads();
  const int twbase = wid * 7 * 256;   // wave-local LDS base (imm offsets cover j,d)

  const float* xp = f_input + (size_t)b * DD * SS + s0 + 2 * lane;

  float acc0[7], acc1[7];
  #pragma unroll
  for (int j = 0; j < 7; ++j) { acc0[j] = 0.0f; acc1[j] = 0.0f; }

  // depth-8 prefetch double buffer, 8 d's per group
  float2 xb[2][8];
  #pragma unroll
  for (int i = 0; i < 8; ++i) xb[0][i] = *(const float2*)(xp + (size_t)i * SS);

  float s2_0 = 0.0f, s2_1 = 0.0f;
  int buf = 0;
  for (int part = 0; part < 8; ++part) {
    float p0 = 0.0f, p1 = 0.0f;
    #pragma unroll
    for (int dd = 0; dd < 32; dd += 8) {
      const int d0 = part * 32 + dd;
      const int dn = (d0 + 8 < DD) ? (d0 + 8) : 0;  // clamp: harmless redundant prefetch
      #pragma unroll
      for (int i = 0; i < 8; ++i) xb[buf ^ 1][i] = *(const float2*)(xp + (size_t)(dn + i) * SS);
      #pragma unroll
      for (int g = 0; g < 2; ++g) {
        const float2 xa = xb[buf][4 * g + 0], xc2 = xb[buf][4 * g + 1],
                     xc3 = xb[buf][4 * g + 2], xc4 = xb[buf][4 * g + 3];
        // bit-exact chains: d-ascending per (k,s); norm singleton adds asc
        p0 += xa.x * xa.x; p0 += xc2.x * xc2.x; p0 += xc3.x * xc3.x; p0 += xc4.x * xc4.x;
        p1 += xa.y * xa.y; p1 += xc2.y * xc2.y; p1 += xc3.y * xc3.y; p1 += xc4.y * xc4.y;
        #pragma unroll
        for (int j = 0; j < 7; ++j) {
          // wave-uniform LDS address -> ds_read_b128 broadcast (conflict-free)
          const float4 tq = *(const float4*)&tvs[twbase + j * 256 + d0 + 4 * g];
          acc0[j] += xa.x * tq.x; acc0[j] += xc2.x * tq.y;
          acc0[j] += xc3.x * tq.z; acc0[j] += xc4.x * tq.w;
          acc1[j] += xa.y * tq.x; acc1[j] += xc2.y * tq.y;
          acc1[j] += xc3.y * tq.z; acc1[j] += xc4.y * tq.w;
        }
      }
      buf ^= 1;
    }
    s2_0 = (part == 0) ? p0 : (s2_0 + p0);
    s2_1 = (part == 0) ? p1 : (s2_1 + p1);
  }
  const float i0 = 1.0f / fmaxf(sqrtf(s2_0), 1e-12f);
  const float i1 = 1.0f / fmaxf(sqrtf(s2_1), 1e-12f);

  bool m = false;
  const size_t gs = (size_t)b * SS + s0 + 2 * lane;
  #pragma unroll
  for (int j = 0; j < 7; ++j) {
    if (kval[j]) {
      const int k = kb + 8 * j;
      float2 o;
      o.x = acc0[j] * i0;
      o.y = acc1[j] * i1;
      *(float2*)(tpn_t + (size_t)k * BS + gs) = o;
      m = m | (o.x > 0.3f) | (o.y > 0.3f);
    }
  }

  const int w = __any((int)m);
  if (lane == 0) wflag[wid] = w;
  __syncthreads();
  const int blockAny = wflag[0] | wflag[1] | wflag[2] | wflag[3];

  if (t == 0) {
    const int old = atomicOr(&tile_flag[tile], blockAny);
    const int done = atomicAdd(&tile_cnt[tile], 1);
    int dec = 0;
    if (done == 1) {               // second finisher: union is complete
      const int fl = old | blockAny;
      if (fl) {
        const int idx = atomicAdd(surv_cnt, 1);
        if (idx < MAXSURV) surv_list[idx] = tile;
      } else {
        atomicAdd(ae_acc, (float)TS);  // sum_s ||x_n||^2 = TS exactly
        dec = 1;
      }
    }
    decision = dec;
  }
  __syncthreads();
  if (decision) {
    float* ob = out_nn + ((size_t)b * SS + s0) * KK;
    for (int p2 = t; p2 < TS * KK; p2 += 256) ob[p2] = 0.0f;
  }
}

// Fused: blocks [0,800) = per-wave exact top-32 of 1024-elem chunks;
// blocks [800,864) = survivor tiles (nn from tpn_t, out_nn, r1, r2, pred, ae).
__global__ __launch_bounds__(256) void chunk_surv_kernel(
    const float* __restrict__ tpn_t, float* __restrict__ cand,
    const float* __restrict__ f_input, const float* __restrict__ rec1,
    const float* __restrict__ rec2, const int* __restrict__ surv_cnt,
    const int* __restrict__ surv_list, float* __restrict__ out_nn,
    float* __restrict__ predacc, float* __restrict__ ae_acc) {
  __shared__ __align__(16) float NNk[KK * 20];   // [k][s16] stride 20
  __shared__ __align__(16) float R1t[HH * 20];   // [h][s16] stride 20
  __shared__ float nprt[16][17];
  __shared__ float nrm[16], invn[16];
  __shared__ float pm[8 * DD];
  __shared__ float red4[4];

  const int t = threadIdx.x;
  const int lane = t & 63, wid = t >> 6;

  if (blockIdx.x < NCHBLK) {
    // ---------- chunk top-32 path (no LDS, no barriers) ----------
    const int gchunk = blockIdx.x * 4 + wid;
    const int k = gchunk >> 6;
    const int c = gchunk & (NCH - 1);
    const float* row = tpn_t + (size_t)k * BS + c * CHUNK;

    float v[16];
    unsigned key[16];
    #pragma unroll
    for (int j = 0; j < 16; ++j) {
      v[j] = row[lane + j * 64];
      key[j] = fkey(v[j]);
    }
    unsigned T = 0;
    for (int bit = 31; bit >= 0; --bit) {
      const unsigned ct = T | (1u << bit);
      int cnt = 0;
      #pragma unroll
      for (int j = 0; j < 16; ++j) cnt += (key[j] >= ct) ? 1 : 0;
      #pragma unroll
      for (int off = 1; off < 64; off <<= 1) cnt += __shfl_xor(cnt, off);
      if (cnt >= TOPK) T = ct;
    }
    int cg = 0;
    #pragma unroll
    for (int j = 0; j < 16; ++j) cg += (key[j] > T) ? 1 : 0;
    int incl = cg;
    #pragma unroll
    for (int off = 1; off < 64; off <<= 1) {
      int y = __shfl_up(incl, off);
      if (lane >= off) incl += y;
    }
    const int excl = incl - cg;
    const int total_gt = __shfl(incl, 63);

    float* cb = cand + (size_t)gchunk * TOPK;
    int pos = excl;
    #pragma unroll
    for (int j = 0; j < 16; ++j) {
      if (key[j] > T) cb[pos++] = v[j];
    }
    if (lane < TOPK - total_gt) cb[total_gt + lane] = keyval(T);
    return;
  }

  // ---------- survivor path ----------
  const int bid = blockIdx.x - NCHBLK;   // 0..63
  int cnt = *surv_cnt;
  if (cnt > MAXSURV) cnt = MAXSURV;
  const int ntask = NSUB * cnt;

  for (int task = bid; task < ntask; task += 64) {
    const int tile = surv_list[task / NSUB];
    const int q = task % NSUB;
    const int b = tile >> 2;
    const int s0 = (tile & 3) * TS + q * 16;
    const float* fb = f_input + (size_t)b * DD * SS;
    const size_t gs0 = (size_t)b * SS + s0;

    // stage tpn rows for these 16 s
    for (int p = t; p < KK * 16; p += 256) {
      const int k = p >> 4, ss = p & 15;
      NNk[k * 20 + ss] = tpn_t[(size_t)k * BS + gs0 + ss];
    }
    // cooperative norms: 16 d-parts x 16 s, 16 unrolled independent loads each
    {
      const int ss = t & 15, part = t >> 4;
      const float* xc = fb + (size_t)(part * 16) * SS + s0 + ss;
      float p = 0.0f;
      #pragma unroll
      for (int i = 0; i < 16; ++i) {
        const float v = xc[(size_t)i * SS];
        p += v * v;
      }
      nprt[part][ss] = p;
    }
    __syncthreads();
    if (t < 16) {
      float s2 = 0.0f;
      #pragma unroll
      for (int i = 0; i < 16; ++i) s2 += nprt[i][t];
      const float n = fmaxf(sqrtf(s2), 1e-12f);
      nrm[t] = n;
      invn[t] = 1.0f / n;
      float sm = 0.0f;
      for (int k = 0; k < KK; ++k) {
        const float tpn = NNk[k * 20 + t];
        sm += (tpn > 0.3f) ? tpn * n : 0.0f;
      }
      const float idv = 1.0f / (sm + 0.001f + 1e-8f);
      for (int k = 0; k < KK; ++k) {
        const float tpn = NNk[k * 20 + t];
        NNk[k * 20 + t] = (tpn > 0.3f) ? tpn * n * idv : 0.0f;
      }
    }
    __syncthreads();

    // write out_nn for these 16 s (scalar: out_nn only 4B-aligned)
    for (int p = t; p < 16 * KK; p += 256) {
      const int ss = p / KK, k = p - ss * KK;
      out_nn[(gs0 + ss) * KK + k] = NNk[k * 20 + ss];
    }

    // phase 4: r1[h=t][s] = relu(nn . rec1)
    {
      float a[16];
      #pragma unroll
      for (int i = 0; i < 16; ++i) a[i] = 0.0f;
      #pragma unroll 2
      for (int k = 0; k < KK; ++k) {
        const float r = rec1[k * HH + t];
        const float4* np = (const float4*)&NNk[k * 20];
        #pragma unroll
        for (int qq = 0; qq < 4; ++qq) {
          const float4 nv = np[qq];
          a[qq * 4 + 0] += nv.x * r;
          a[qq * 4 + 1] += nv.y * r;
          a[qq * 4 + 2] += nv.z * r;
          a[qq * 4 + 3] += nv.w * r;
        }
      }
      #pragma unroll
      for (int i = 0; i < 16; ++i) R1t[t * 20 + i] = fmaxf(a[i], 0.0f);
    }
    __syncthreads();

    // phase 5: r2 = r1 @ rec2; per thread 2s x 8d; h unrolled x8 with batch prefetch
    const int tx = t & 31, ty = t >> 5;
    const int d0 = tx * 8, sb = ty * 2;
    float c2[2][8];
    #pragma unroll
    for (int i = 0; i < 2; ++i)
      #pragma unroll
      for (int j = 0; j < 8; ++j) c2[i][j] = 0.0f;
    for (int h0 = 0; h0 < HH; h0 += 8) {
      float4 B0[8], B1[8];
      #pragma unroll
      for (int u = 0; u < 8; ++u) {
        B0[u] = *(const float4*)(rec2 + (h0 + u) * DD + d0);
        B1[u] = *(const float4*)(rec2 + (h0 + u) * DD + d0 + 4);
      }
      #pragma unroll
      for (int u = 0; u < 8; ++u) {
        const float2 a01 = *(const float2*)(&R1t[(h0 + u) * 20 + sb]);
        const float bv[8] = {B0[u].x, B0[u].y, B0[u].z, B0[u].w,
                             B1[u].x, B1[u].y, B1[u].z, B1[u].w};
        #pragma unroll
        for (int j = 0; j < 8; ++j) {
          c2[0][j] += a01.x * bv[j];
          c2[1][j] += a01.y * bv[j];
        }
      }
    }
    #pragma unroll
    for (int j = 0; j < 8; ++j) pm[ty * DD + d0 + j] = c2[0][j] + c2[1][j];
    __syncthreads();
    {
      float sum = 0.0f;
      #pragma unroll
      for (int r = 0; r < 8; ++r) sum += pm[r * DD + t];
      atomicAdd(&predacc[(size_t)b * DD + t], sum);
    }
    float e = 0.0f;
    #pragma unroll
    for (int j = 0; j < 8; ++j) {
      #pragma unroll
      for (int i = 0; i < 2; ++i) {
        const float x = fb[(size_t)(d0 + j) * SS + s0 + sb + i];
        const float diff = x * invn[sb + i] - c2[i][j];
        e += diff * diff;
      }
    }
    #pragma unroll
    for (int off = 1; off < 64; off <<= 1) e += __shfl_xor(e, off);
    if (lane == 0) red4[wid] = e;
    __syncthreads();
    if (t == 0) atomicAdd(ae_acc, red4[0] + red4[1] + red4[2] + red4[3]);
    __syncthreads();  // LDS reuse next task
  }
}

// Fused: blocks [0,128) pred head (+block0: far, out[256], ae);
// blocks [128,178) top-32 merge per concept; last merge finisher writes out[257].
__global__ __launch_bounds__(256) void merge_finalize_kernel(
    const float* __restrict__ cand, const float* __restrict__ predacc,
    const float* __restrict__ Wc, const float* __restrict__ bc,
    const float* __restrict__ ae_acc, float* __restrict__ sim_acc,
    unsigned* __restrict__ sim_done, const float* __restrict__ tvn,
    float* __restrict__ out) {
  __shared__ float r0[256], r1[256];
  const int blk = blockIdx.x;
  const int t = threadIdx.x;

  if (blk >= BB) {
    // ---- merge path: one wave, concept k ----
    if (t < 64) {
      const int k = blk - BB;
      const int lane = t;
      const float* row = cand + (size_t)k * (NCH * TOPK);
      float v[32];
      unsigned key[32];
      #pragma unroll
      for (int j = 0; j < 32; ++j) {
        v[j] = row[lane + j * 64];
        key[j] = fkey(v[j]);
      }
      unsigned T = 0;
      for (int bit = 31; bit >= 0; --bit) {
        const unsigned ct = T | (1u << bit);
        int cnt = 0;
        #pragma unroll
        for (int j = 0; j < 32; ++j) cnt += (key[j] >= ct) ? 1 : 0;
        #pragma unroll
        for (int off = 1; off < 64; off <<= 1) cnt += __shfl_xor(cnt, off);
        if (cnt >= TOPK) T = ct;
      }
      float s = 0.0f;
      int cgt = 0;
      #pragma unroll
      for (int j = 0; j < 32; ++j) {
        if (key[j] > T) { s += v[j]; cgt++; }
      }
      #pragma unroll
      for (int off = 1; off < 64; off <<= 1) {
        s += __shfl_xor(s, off);
        cgt += __shfl_xor(cgt, off);
      }
      if (lane == 0) {
        atomicAdd(sim_acc, s + (float)(TOPK - cgt) * keyval(T));
        __threadfence();
        const unsigned c = atomicAdd(sim_done, 1u);
        if (c == KK - 1) {               // last finisher: total is complete
          __threadfence();
          const float tot = atomicAdd(sim_acc, 0.0f);
          out[257] = -tot * (1.0f / (float)(KK * TOPK));
        }
      }
    }
    return;
  }

  // ---- finalize path: pred head for b = blk ----
  const float s = predacc[(size_t)blk * DD + t];
  r0[t] = s * Wc[t * 2 + 0];
  r1[t] = s * Wc[t * 2 + 1];
  __syncthreads();
  for (int off = 128; off > 0; off >>= 1) {
    if (t < off) { r0[t] += r0[t + off]; r1[t] += r1[t + off]; }
    __syncthreads();
  }
  if (t == 0) {
    out[blk * 2 + 0] = r0[0] * (1.0f / (float)SS) + bc[0];
    out[blk * 2 + 1] = r1[0] * (1.0f / (float)SS) + bc[1];
    if (blk == 0) {
      out[256] = 0.0f;
      out[OUT_AE_IDX] = (*ae_acc) * (1.0f / ((float)BB * (float)SS * (float)DD));
    }
  }
  if (blk == 0) {
    // concept_far: sum(G) = sum_d (rowsum_d)^2 since G = tvn^T tvn
    __syncthreads();
    float rs = 0.0f;
    for (int k = 0; k < KK; ++k) rs += tvn[t * KK + k];
    r0[t] = rs * rs;
    __syncthreads();
    for (int off = 128; off > 0; off >>= 1) {
      if (t < off) r0[t] += r0[t + off];
      __syncthreads();
    }
    if (t == 0) out[258] = (r0[0] - (float)KK) / ((float)KK * (float)KK);
  }
}

extern "C" void kernel_launch(void* const* d_in, const int* in_sizes, int n_in,
                              void* d_out, int out_size, void* d_ws, size_t ws_size,
                              hipStream_t stream) {
  (void)in_sizes; (void)n_in; (void)out_size; (void)ws_size;
  const float* f_input = (const float*)d_in[0];
  const float* tv = (const float*)d_in[2];
  const float* rec1 = (const float*)d_in[3];
  const float* rec2 = (const float*)d_in[4];
  const float* Wc = (const float*)d_in[5];
  const float* bc = (const float*)d_in[6];

  float* out = (float*)d_out;
  float* ws = (float*)d_ws;
  float* tvn = ws + TVN_OFF;
  float* tvnT = ws + TVNT_OFF;
  float* tpn_t = ws + TPNT_OFF;
  float* predacc = ws + PREDACC_OFF;
  float* ae_acc = ws + AE_OFF;
  float* sim_acc = ws + SIM_OFF;
  int* surv_cnt = (int*)(ws + CNT_OFF);
  unsigned* sim_done = (unsigned*)(ws + SIMD_OFF);
  int* tile_flag = (int*)(ws + TFLAG_OFF);
  int* tile_cnt = (int*)(ws + TCNT_OFF);
  int* surv_list = (int*)(ws + LIST_OFF);
  float* cand = ws + CAND_OFF;

  tvn_kernel<<<KK, 256, 0, stream>>>(tv, tvn, tvnT, predacc);
  main_kernel<<<NBLK, 256, 0, stream>>>(f_input, tvnT, out + OUT_NN_OFF, tpn_t,
                                        ae_acc, surv_cnt, surv_list,
                                        tile_flag, tile_cnt);
  chunk_surv_kernel<<<NCHBLK + 64, 256, 0, stream>>>(
      tpn_t, cand, f_input, rec1, rec2, surv_cnt, surv_list,
      out + OUT_NN_OFF, predacc, ae_acc);
  merge_finalize_kernel<<<BB + KK, 256, 0, stream>>>(
      cand, predacc, Wc, bc, ae_acc, sim_acc, sim_done, tvn, out);
}

// Round 8
// 242.842 us; speedup vs baseline: 1.2401x; 1.1098x over previous
//
#include <hip/hip_runtime.h>
#include <math.h>

#define BB 128
#define DD 256
#define SS 512
#define KK 50
#define HH 256
#define TS 128               // s-tile
#define NTILES (BB * SS / TS) // 512
#define NBLK (NTILES * 4)    // 2048 (x4 k-quarters)
#define BS (BB * SS)         // 65536

#define CHUNK 1024
#define NCH (BS / CHUNK)     // 64
#define NCHBLK (KK * NCH / 4) // 800 chunk blocks
#define TOPK 32
#define MAXSURV 512
#define NSUB (TS / 16)       // 8 survivor subtiles per tile

// workspace layout (float offsets)
#define TVN_OFF 0
#define TVNT_OFF (TVN_OFF + DD * KK)          // 12800
#define TPNT_OFF (TVNT_OFF + KK * DD)         // 25600
#define PREDACC_OFF (TPNT_OFF + KK * BS)
#define AE_OFF (PREDACC_OFF + BB * DD)        // +32768
#define SIM_OFF (AE_OFF + 1)
#define CNT_OFF (AE_OFF + 2)                  // surv_cnt
#define SIMD_OFF (AE_OFF + 3)                 // sim_done counter
#define TFLAG_OFF (AE_OFF + 4)                // NTILES ints (unused; kept for layout)
#define TCNT_OFF (TFLAG_OFF + NTILES)         // NTILES ints: packed count|flag word
#define NZERO (BB * DD + 4 + 2 * NTILES)      // contiguous zero region from PREDACC
#define LIST_OFF (TCNT_OFF + NTILES)          // MAXSURV ints (no zeroing needed)
#define CAND_OFF (LIST_OFF + MAXSURV)         // KK*NCH*TOPK floats

// out layout: pred[0:256), 0.0@256, sim@257, far@258, nn[259:259+3276800), ae@3277059
#define OUT_NN_OFF 259
#define OUT_AE_IDX (OUT_NN_OFF + KK * BS)

__device__ __forceinline__ unsigned fkey(float f) {
  unsigned u = __float_as_uint(f);
  return (u & 0x80000000u) ? ~u : (u | 0x80000000u);
}
__device__ __forceinline__ float keyval(unsigned T) {
  unsigned u = (T & 0x80000000u) ? (T & 0x7FFFFFFFu) : ~T;
  return __uint_as_float(u);
}

// tvn + transposed copy; also zeroes predacc/scalars/tile words (replaces memset)
__global__ __launch_bounds__(256) void tvn_kernel(const float* __restrict__ tv,
                                                  float* __restrict__ tvn,
                                                  float* __restrict__ tvnT,
                                                  float* __restrict__ zbase) {
  __shared__ float red[256];
  const int k = blockIdx.x, t = threadIdx.x;
  {
    const int gid = k * 256 + t;                 // 12800 threads total
    for (int i = gid; i < NZERO; i += KK * 256) zbase[i] = 0.0f;
  }
  float v = tv[t * KK + k];
  red[t] = v * v;
  __syncthreads();
  for (int off = 128; off > 0; off >>= 1) {
    if (t < off) red[t] += red[t + off];
    __syncthreads();
  }
  float inv = 1.0f / fmaxf(sqrtf(red[0]), 1e-12f);
  const float nv = v * inv;
  tvn[t * KK + k] = nv;
  tvnT[k * DD + t] = nv;
}

// blk = tile*4 + quarter. Wave owns k = kb + 16j (kb = quarter*4+wid, j<4);
// thread = s-pair (float2). x: coalesced dwordx2 + depth-8 prefetch (R2 path).
// R8 FIX vs R7: tile accounting is a SINGLE packed atomic —
//   old = atomicAdd(&tile_cnt[tile], (blockAny<<16)|1). R7 used two relaxed
//   atomics to different addresses (Or flag, Add count); nothing orders
//   another block's Or before its Add as seen by the last finisher -> stale
//   union -> surviving tiles zero-filled (the R7 all-zeros failure, ae=1/256).
//   One atomic word = one serialization point; last arriver (old&0xFFFF==3)
//   provably sees all prior flags in old>>16.
// PERF THEORY (unchanged from R7): at 7 rows/wave the tq s_load groups could
//   only double-buffer (SGPR=112 at cap); prefetch distance 128cy < ~200cy
//   K$-miss latency -> 47% stall. At 4 rows/wave a group is 16 SGPRs -> 3-4
//   groups in flight -> distance >= 240cy. x read 4x/tile (cache-elastic, R3).
// Per-(k,s) FP chains identical to verified baseline.
__global__ __launch_bounds__(256, 4) void main_kernel(
    const float* __restrict__ f_input, const float* __restrict__ tvnT,
    float* __restrict__ out_nn, float* __restrict__ tpn_t,
    float* __restrict__ ae_acc, int* __restrict__ surv_cnt,
    int* __restrict__ surv_list, int* __restrict__ tile_flag,
    int* __restrict__ tile_cnt) {
  __shared__ int wflag[4];
  __shared__ int decision;   // 1 = zero-fill tile, 0 = nothing
  (void)tile_flag;           // superseded by packed tile_cnt word

  const int blk = blockIdx.x;
  const int tile = blk >> 2;
  const int quarter = blk & 3;
  const int b = tile >> 2;
  const int s0 = (tile & 3) * TS;
  const int t = threadIdx.x;
  const int lane = t & 63;
  const int wid = t >> 6;
  const int kb = __builtin_amdgcn_readfirstlane(quarter * 4 + wid);  // 0..15, wave-uniform

  const float* tvk[4];
  bool kval[4];
  #pragma unroll
  for (int j = 0; j < 4; ++j) {
    const int k = kb + 16 * j;
    kval[j] = (k < KK);
    tvk[j] = tvnT + (size_t)(kval[j] ? k : (KK - 1)) * DD;
  }

  const float* xp = f_input + (size_t)b * DD * SS + s0 + 2 * lane;

  float acc0[4], acc1[4];
  #pragma unroll
  for (int j = 0; j < 4; ++j) { acc0[j] = 0.0f; acc1[j] = 0.0f; }

  // depth-8 prefetch double buffer, 8 d's per group
  float2 xb[2][8];
  #pragma unroll
  for (int i = 0; i < 8; ++i) xb[0][i] = *(const float2*)(xp + (size_t)i * SS);

  float s2_0 = 0.0f, s2_1 = 0.0f;
  int buf = 0;
  for (int part = 0; part < 8; ++part) {
    float p0 = 0.0f, p1 = 0.0f;
    #pragma unroll
    for (int dd = 0; dd < 32; dd += 8) {
      const int d0 = part * 32 + dd;
      const int dn = (d0 + 8 < DD) ? (d0 + 8) : 0;  // clamp: harmless redundant prefetch
      #pragma unroll
      for (int i = 0; i < 8; ++i) xb[buf ^ 1][i] = *(const float2*)(xp + (size_t)(dn + i) * SS);
      #pragma unroll
      for (int g = 0; g < 2; ++g) {
        const float2 xa = xb[buf][4 * g + 0], xc2 = xb[buf][4 * g + 1],
                     xc3 = xb[buf][4 * g + 2], xc4 = xb[buf][4 * g + 3];
        // bit-exact chains: d-ascending per (k,s); norm singleton adds asc
        p0 += xa.x * xa.x; p0 += xc2.x * xc2.x; p0 += xc3.x * xc3.x; p0 += xc4.x * xc4.x;
        p1 += xa.y * xa.y; p1 += xc2.y * xc2.y; p1 += xc3.y * xc3.y; p1 += xc4.y * xc4.y;
        #pragma unroll
        for (int j = 0; j < 4; ++j) {
          const float4 tq = *(const float4*)(tvk[j] + d0 + 4 * g);  // wave-uniform -> s_load
          acc0[j] += xa.x * tq.x; acc0[j] += xc2.x * tq.y;
          acc0[j] += xc3.x * tq.z; acc0[j] += xc4.x * tq.w;
          acc1[j] += xa.y * tq.x; acc1[j] += xc2.y * tq.y;
          acc1[j] += xc3.y * tq.z; acc1[j] += xc4.y * tq.w;
        }
      }
      buf ^= 1;
    }
    s2_0 = (part == 0) ? p0 : (s2_0 + p0);
    s2_1 = (part == 0) ? p1 : (s2_1 + p1);
  }
  const float i0 = 1.0f / fmaxf(sqrtf(s2_0), 1e-12f);
  const float i1 = 1.0f / fmaxf(sqrtf(s2_1), 1e-12f);

  bool m = false;
  const size_t gs = (size_t)b * SS + s0 + 2 * lane;
  #pragma unroll
  for (int j = 0; j < 4; ++j) {
    if (kval[j]) {
      const int k = kb + 16 * j;
      float2 o;
      o.x = acc0[j] * i0;
      o.y = acc1[j] * i1;
      *(float2*)(tpn_t + (size_t)k * BS + gs) = o;
      m = m | (o.x > 0.3f) | (o.y > 0.3f);
    }
  }

  const int w = __any((int)m);
  if (lane == 0) wflag[wid] = w;
  __syncthreads();
  const int blockAny = (wflag[0] | wflag[1] | wflag[2] | wflag[3]) ? 1 : 0;

  if (t == 0) {
    // single packed atomic: low 16 bits = arrival count, high bits = flag sum
    const int old = atomicAdd(&tile_cnt[tile], (blockAny << 16) | 1);
    int dec = 0;
    if ((old & 0xFFFF) == 3) {     // last of 4 arrivers: union is complete
      const int fl = (old >> 16) | blockAny;
      if (fl) {
        const int idx = atomicAdd(surv_cnt, 1);
        if (idx < MAXSURV) surv_list[idx] = tile;
      } else {
        atomicAdd(ae_acc, (float)TS);  // sum_s ||x_n||^2 = TS exactly
        dec = 1;
      }
    }
    decision = dec;
  }
  __syncthreads();
  if (decision) {
    float* ob = out_nn + ((size_t)b * SS + s0) * KK;
    for (int p2 = t; p2 < TS * KK; p2 += 256) ob[p2] = 0.0f;
  }
}

// Fused: blocks [0,800) = per-wave exact top-32 of 1024-elem chunks;
// blocks [800,864) = survivor tiles (nn from tpn_t, out_nn, r1, r2, pred, ae).
__global__ __launch_bounds__(256) void chunk_surv_kernel(
    const float* __restrict__ tpn_t, float* __restrict__ cand,
    const float* __restrict__ f_input, const float* __restrict__ rec1,
    const float* __restrict__ rec2, const int* __restrict__ surv_cnt,
    const int* __restrict__ surv_list, float* __restrict__ out_nn,
    float* __restrict__ predacc, float* __restrict__ ae_acc) {
  __shared__ __align__(16) float NNk[KK * 20];   // [k][s16] stride 20
  __shared__ __align__(16) float R1t[HH * 20];   // [h][s16] stride 20
  __shared__ float nprt[16][17];
  __shared__ float nrm[16], invn[16];
  __shared__ float pm[8 * DD];
  __shared__ float red4[4];

  const int t = threadIdx.x;
  const int lane = t & 63, wid = t >> 6;

  if (blockIdx.x < NCHBLK) {
    // ---------- chunk top-32 path (no LDS, no barriers) ----------
    const int gchunk = blockIdx.x * 4 + wid;
    const int k = gchunk >> 6;
    const int c = gchunk & (NCH - 1);
    const float* row = tpn_t + (size_t)k * BS + c * CHUNK;

    float v[16];
    unsigned key[16];
    #pragma unroll
    for (int j = 0; j < 16; ++j) {
      v[j] = row[lane + j * 64];
      key[j] = fkey(v[j]);
    }
    unsigned T = 0;
    for (int bit = 31; bit >= 0; --bit) {
      const unsigned ct = T | (1u << bit);
      int cnt = 0;
      #pragma unroll
      for (int j = 0; j < 16; ++j) cnt += (key[j] >= ct) ? 1 : 0;
      #pragma unroll
      for (int off = 1; off < 64; off <<= 1) cnt += __shfl_xor(cnt, off);
      if (cnt >= TOPK) T = ct;
    }
    int cg = 0;
    #pragma unroll
    for (int j = 0; j < 16; ++j) cg += (key[j] > T) ? 1 : 0;
    int incl = cg;
    #pragma unroll
    for (int off = 1; off < 64; off <<= 1) {
      int y = __shfl_up(incl, off);
      if (lane >= off) incl += y;
    }
    const int excl = incl - cg;
    const int total_gt = __shfl(incl, 63);

    float* cb = cand + (size_t)gchunk * TOPK;
    int pos = excl;
    #pragma unroll
    for (int j = 0; j < 16; ++j) {
      if (key[j] > T) cb[pos++] = v[j];
    }
    if (lane < TOPK - total_gt) cb[total_gt + lane] = keyval(T);
    return;
  }

  // ---------- survivor path ----------
  const int bid = blockIdx.x - NCHBLK;   // 0..63
  int cnt = *surv_cnt;
  if (cnt > MAXSURV) cnt = MAXSURV;
  const int ntask = NSUB * cnt;

  for (int task = bid; task < ntask; task += 64) {
    const int tile = surv_list[task / NSUB];
    const int q = task % NSUB;
    const int b = tile >> 2;
    const int s0 = (tile & 3) * TS + q * 16;
    const float* fb = f_input + (size_t)b * DD * SS;
    const size_t gs0 = (size_t)b * SS + s0;

    // stage tpn rows for these 16 s
    for (int p = t; p < KK * 16; p += 256) {
      const int k = p >> 4, ss = p & 15;
      NNk[k * 20 + ss] = tpn_t[(size_t)k * BS + gs0 + ss];
    }
    // cooperative norms: 16 d-parts x 16 s, 16 unrolled independent loads each
    {
      const int ss = t & 15, part = t >> 4;
      const float* xc = fb + (size_t)(part * 16) * SS + s0 + ss;
      float p = 0.0f;
      #pragma unroll
      for (int i = 0; i < 16; ++i) {
        const float v = xc[(size_t)i * SS];
        p += v * v;
      }
      nprt[part][ss] = p;
    }
    __syncthreads();
    if (t < 16) {
      float s2 = 0.0f;
      #pragma unroll
      for (int i = 0; i < 16; ++i) s2 += nprt[i][t];
      const float n = fmaxf(sqrtf(s2), 1e-12f);
      nrm[t] = n;
      invn[t] = 1.0f / n;
      float sm = 0.0f;
      for (int k = 0; k < KK; ++k) {
        const float tpn = NNk[k * 20 + t];
        sm += (tpn > 0.3f) ? tpn * n : 0.0f;
      }
      const float idv = 1.0f / (sm + 0.001f + 1e-8f);
      for (int k = 0; k < KK; ++k) {
        const float tpn = NNk[k * 20 + t];
        NNk[k * 20 + t] = (tpn > 0.3f) ? tpn * n * idv : 0.0f;
      }
    }
    __syncthreads();

    // write out_nn for these 16 s (scalar: out_nn only 4B-aligned)
    for (int p = t; p < 16 * KK; p += 256) {
      const int ss = p / KK, k = p - ss * KK;
      out_nn[(gs0 + ss) * KK + k] = NNk[k * 20 + ss];
    }

    // phase 4: r1[h=t][s] = relu(nn . rec1)
    {
      float a[16];
      #pragma unroll
      for (int i = 0; i < 16; ++i) a[i] = 0.0f;
      #pragma unroll 2
      for (int k = 0; k < KK; ++k) {
        const float r = rec1[k * HH + t];
        const float4* np = (const float4*)&NNk[k * 20];
        #pragma unroll
        for (int qq = 0; qq < 4; ++qq) {
          const float4 nv = np[qq];
          a[qq * 4 + 0] += nv.x * r;
          a[qq * 4 + 1] += nv.y * r;
          a[qq * 4 + 2] += nv.z * r;
          a[qq * 4 + 3] += nv.w * r;
        }
      }
      #pragma unroll
      for (int i = 0; i < 16; ++i) R1t[t * 20 + i] = fmaxf(a[i], 0.0f);
    }
    __syncthreads();

    // phase 5: r2 = r1 @ rec2; per thread 2s x 8d; h unrolled x8 with batch prefetch
    const int tx = t & 31, ty = t >> 5;
    const int d0 = tx * 8, sb = ty * 2;
    float c2[2][8];
    #pragma unroll
    for (int i = 0; i < 2; ++i)
      #pragma unroll
      for (int j = 0; j < 8; ++j) c2[i][j] = 0.0f;
    for (int h0 = 0; h0 < HH; h0 += 8) {
      float4 B0[8], B1[8];
      #pragma unroll
      for (int u = 0; u < 8; ++u) {
        B0[u] = *(const float4*)(rec2 + (h0 + u) * DD + d0);
        B1[u] = *(const float4*)(rec2 + (h0 + u) * DD + d0 + 4);
      }
      #pragma unroll
      for (int u = 0; u < 8; ++u) {
        const float2 a01 = *(const float2*)(&R1t[(h0 + u) * 20 + sb]);
        const float bv[8] = {B0[u].x, B0[u].y, B0[u].z, B0[u].w,
                             B1[u].x, B1[u].y, B1[u].z, B1[u].w};
        #pragma unroll
        for (int j = 0; j < 8; ++j) {
          c2[0][j] += a01.x * bv[j];
          c2[1][j] += a01.y * bv[j];
        }
      }
    }
    #pragma unroll
    for (int j = 0; j < 8; ++j) pm[ty * DD + d0 + j] = c2[0][j] + c2[1][j];
    __syncthreads();
    {
      float sum = 0.0f;
      #pragma unroll
      for (int r = 0; r < 8; ++r) sum += pm[r * DD + t];
      atomicAdd(&predacc[(size_t)b * DD + t], sum);
    }
    float e = 0.0f;
    #pragma unroll
    for (int j = 0; j < 8; ++j) {
      #pragma unroll
      for (int i = 0; i < 2; ++i) {
        const float x = fb[(size_t)(d0 + j) * SS + s0 + sb + i];
        const float diff = x * invn[sb + i] - c2[i][j];
        e += diff * diff;
      }
    }
    #pragma unroll
    for (int off = 1; off < 64; off <<= 1) e += __shfl_xor(e, off);
    if (lane == 0) red4[wid] = e;
    __syncthreads();
    if (t == 0) atomicAdd(ae_acc, red4[0] + red4[1] + red4[2] + red4[3]);
    __syncthreads();  // LDS reuse next task
  }
}

// Fused: blocks [0,128) pred head (+block0: far, out[256], ae);
// blocks [128,178) top-32 merge per concept; last merge finisher writes out[257].
__global__ __launch_bounds__(256) void merge_finalize_kernel(
    const float* __restrict__ cand, const float* __restrict__ predacc,
    const float* __restrict__ Wc, const float* __restrict__ bc,
    const float* __restrict__ ae_acc, float* __restrict__ sim_acc,
    unsigned* __restrict__ sim_done, const float* __restrict__ tvn,
    float* __restrict__ out) {
  __shared__ float r0[256], r1[256];
  const int blk = blockIdx.x;
  const int t = threadIdx.x;

  if (blk >= BB) {
    // ---- merge path: one wave, concept k ----
    if (t < 64) {
      const int k = blk - BB;
      const int lane = t;
      const float* row = cand + (size_t)k * (NCH * TOPK);
      float v[32];
      unsigned key[32];
      #pragma unroll
      for (int j = 0; j < 32; ++j) {
        v[j] = row[lane + j * 64];
        key[j] = fkey(v[j]);
      }
      unsigned T = 0;
      for (int bit = 31; bit >= 0; --bit) {
        const unsigned ct = T | (1u << bit);
        int cnt = 0;
        #pragma unroll
        for (int j = 0; j < 32; ++j) cnt += (key[j] >= ct) ? 1 : 0;
        #pragma unroll
        for (int off = 1; off < 64; off <<= 1) cnt += __shfl_xor(cnt, off);
        if (cnt >= TOPK) T = ct;
      }
      float s = 0.0f;
      int cgt = 0;
      #pragma unroll
      for (int j = 0; j < 32; ++j) {
        if (key[j] > T) { s += v[j]; cgt++; }
      }
      #pragma unroll
      for (int off = 1; off < 64; off <<= 1) {
        s += __shfl_xor(s, off);
        cgt += __shfl_xor(cgt, off);
      }
      if (lane == 0) {
        atomicAdd(sim_acc, s + (float)(TOPK - cgt) * keyval(T));
        __threadfence();
        const unsigned c = atomicAdd(sim_done, 1u);
        if (c == KK - 1) {               // last finisher: total is complete
          __threadfence();
          const float tot = atomicAdd(sim_acc, 0.0f);
          out[257] = -tot * (1.0f / (float)(KK * TOPK));
        }
      }
    }
    return;
  }

  // ---- finalize path: pred head for b = blk ----
  const float s = predacc[(size_t)blk * DD + t];
  r0[t] = s * Wc[t * 2 + 0];
  r1[t] = s * Wc[t * 2 + 1];
  __syncthreads();
  for (int off = 128; off > 0; off >>= 1) {
    if (t < off) { r0[t] += r0[t + off]; r1[t] += r1[t + off]; }
    __syncthreads();
  }
  if (t == 0) {
    out[blk * 2 + 0] = r0[0] * (1.0f / (float)SS) + bc[0];
    out[blk * 2 + 1] = r1[0] * (1.0f / (float)SS) + bc[1];
    if (blk == 0) {
      out[256] = 0.0f;
      out[OUT_AE_IDX] = (*ae_acc) * (1.0f / ((float)BB * (float)SS * (float)DD));
    }
  }
  if (blk == 0) {
    // concept_far: sum(G) = sum_d (rowsum_d)^2 since G = tvn^T tvn
    __syncthreads();
    float rs = 0.0f;
    for (int k = 0; k < KK; ++k) rs += tvn[t * KK + k];
    r0[t] = rs * rs;
    __syncthreads();
    for (int off = 128; off > 0; off >>= 1) {
      if (t < off) r0[t] += r0[t + off];
      __syncthreads();
    }
    if (t == 0) out[258] = (r0[0] - (float)KK) / ((float)KK * (float)KK);
  }
}

extern "C" void kernel_launch(void* const* d_in, const int* in_sizes, int n_in,
                              void* d_out, int out_size, void* d_ws, size_t ws_size,
                              hipStream_t stream) {
  (void)in_sizes; (void)n_in; (void)out_size; (void)ws_size;
  const float* f_input = (const float*)d_in[0];
  const float* tv = (const float*)d_in[2];
  const float* rec1 = (const float*)d_in[3];
  const float* rec2 = (const float*)d_in[4];
  const float* Wc = (const float*)d_in[5];
  const float* bc = (const float*)d_in[6];

  float* out = (float*)d_out;
  float* ws = (float*)d_ws;
  float* tvn = ws + TVN_OFF;
  float* tvnT = ws + TVNT_OFF;
  float* tpn_t = ws + TPNT_OFF;
  float* predacc = ws + PREDACC_OFF;
  float* ae_acc = ws + AE_OFF;
  float* sim_acc = ws + SIM_OFF;
  int* surv_cnt = (int*)(ws + CNT_OFF);
  unsigned* sim_done = (unsigned*)(ws + SIMD_OFF);
  int* tile_flag = (int*)(ws + TFLAG_OFF);
  int* tile_cnt = (int*)(ws + TCNT_OFF);
  int* surv_list = (int*)(ws + LIST_OFF);
  float* cand = ws + CAND_OFF;

  tvn_kernel<<<KK, 256, 0, stream>>>(tv, tvn, tvnT, predacc);
  main_kernel<<<NBLK, 256, 0, stream>>>(f_input, tvnT, out + OUT_NN_OFF, tpn_t,
                                        ae_acc, surv_cnt, surv_list,
                                        tile_flag, tile_cnt);
  chunk_surv_kernel<<<NCHBLK + 64, 256, 0, stream>>>(
      tpn_t, cand, f_input, rec1, rec2, surv_cnt, surv_list,
      out + OUT_NN_OFF, predacc, ae_acc);
  merge_finalize_kernel<<<BB + KK, 256, 0, stream>>>(
      cand, predacc, Wc, bc, ae_acc, sim_acc, sim_done, tvn, out);
}

// Round 9
// 225.027 us; speedup vs baseline: 1.3383x; 1.0792x over previous
//
#include <hip/hip_runtime.h>
#include <math.h>

#define BB 128
#define DD 256
#define SS 512
#define KK 50
#define HH 256
#define TS 128               // s-tile
#define NTILES (BB * SS / TS) // 512
#define NBLK (NTILES * 2)    // 1024 (x2 k-halves)
#define BS (BB * SS)         // 65536

#define CHUNK 1024
#define NCH (BS / CHUNK)     // 64
#define NCHBLK (KK * NCH / 4) // 800 chunk blocks
#define TOPK 32
#define MAXSURV 512
#define NSUB (TS / 16)       // 8 survivor subtiles per tile

// workspace layout (float offsets)
#define TVN_OFF 0
#define TVNT_OFF (TVN_OFF + DD * KK)          // 12800
#define TPNT_OFF (TVNT_OFF + KK * DD)         // 25600
#define PREDACC_OFF (TPNT_OFF + KK * BS)
#define AE_OFF (PREDACC_OFF + BB * DD)        // +32768
#define SIM_OFF (AE_OFF + 1)
#define CNT_OFF (AE_OFF + 2)                  // surv_cnt
#define SIMD_OFF (AE_OFF + 3)                 // sim_done counter
#define TFLAG_OFF (AE_OFF + 4)                // NTILES ints (unused; kept for layout)
#define TCNT_OFF (TFLAG_OFF + NTILES)         // NTILES ints: packed count|flag word
#define NZERO (BB * DD + 4 + 2 * NTILES)      // contiguous zero region from PREDACC
#define LIST_OFF (TCNT_OFF + NTILES)          // MAXSURV ints (no zeroing needed)
#define CAND_OFF (LIST_OFF + MAXSURV)         // KK*NCH*TOPK floats

// out layout: pred[0:256), 0.0@256, sim@257, far@258, nn[259:259+3276800), ae@3277059
#define OUT_NN_OFF 259
#define OUT_AE_IDX (OUT_NN_OFF + KK * BS)

__device__ __forceinline__ unsigned fkey(float f) {
  unsigned u = __float_as_uint(f);
  return (u & 0x80000000u) ? ~u : (u | 0x80000000u);
}
__device__ __forceinline__ float keyval(unsigned T) {
  unsigned u = (T & 0x80000000u) ? (T & 0x7FFFFFFFu) : ~T;
  return __uint_as_float(u);
}

// tvn + transposed copy; also zeroes predacc/scalars/tile words (replaces memset)
__global__ __launch_bounds__(256) void tvn_kernel(const float* __restrict__ tv,
                                                  float* __restrict__ tvn,
                                                  float* __restrict__ tvnT,
                                                  float* __restrict__ zbase) {
  __shared__ float red[256];
  const int k = blockIdx.x, t = threadIdx.x;
  {
    const int gid = k * 256 + t;                 // 12800 threads total
    for (int i = gid; i < NZERO; i += KK * 256) zbase[i] = 0.0f;
  }
  float v = tv[t * KK + k];
  red[t] = v * v;
  __syncthreads();
  for (int off = 128; off > 0; off >>= 1) {
    if (t < off) red[t] += red[t + off];
    __syncthreads();
  }
  float inv = 1.0f / fmaxf(sqrtf(red[0]), 1e-12f);
  const float nv = v * inv;
  tvn[t * KK + k] = nv;
  tvnT[k * DD + t] = nv;
}

// blk = tile*2 + half. Wave owns k = kb + 8j (kb = half*4+wid, j<7); thread = s-pair (float2).
// x: coalesced dwordx2 + depth-8 prefetch double buffer. tvn: wave-uniform s_load.
// EXACT R2 body (65.5 us verified; session ledger: dur tracks HBM bytes at
// ~1.5 TB/s effective for this pattern, and this structure is at the traffic
// floor — x once + tpn/zero-fill writes). ONLY delta vs R2: the tile epilogue
// uses a single packed atomic (count|flag in one word) — R7 proved the old
// two-address atomic pair (Or flag, Add count) has a real ordering race; the
// packed word (verified in R8) closes it at zero cost.
__global__ __launch_bounds__(256, 4) void main_kernel(
    const float* __restrict__ f_input, const float* __restrict__ tvnT,
    float* __restrict__ out_nn, float* __restrict__ tpn_t,
    float* __restrict__ ae_acc, int* __restrict__ surv_cnt,
    int* __restrict__ surv_list, int* __restrict__ tile_flag,
    int* __restrict__ tile_cnt) {
  __shared__ int wflag[4];
  __shared__ int decision;   // 1 = zero-fill tile, 0 = nothing
  (void)tile_flag;           // superseded by packed tile_cnt word

  const int blk = blockIdx.x;
  const int tile = blk >> 1;
  const int half = blk & 1;
  const int b = tile >> 2;
  const int s0 = (tile & 3) * TS;
  const int t = threadIdx.x;
  const int lane = t & 63;
  const int wid = t >> 6;
  const int kb = __builtin_amdgcn_readfirstlane(half * 4 + wid);  // 0..7, wave-uniform

  const float* tvk[7];
  bool kval[7];
  #pragma unroll
  for (int j = 0; j < 7; ++j) {
    const int k = kb + 8 * j;
    kval[j] = (k < KK);
    tvk[j] = tvnT + (size_t)(kval[j] ? k : (KK - 1)) * DD;
  }

  const float* xp = f_input + (size_t)b * DD * SS + s0 + 2 * lane;

  float acc0[7], acc1[7];
  #pragma unroll
  for (int j = 0; j < 7; ++j) { acc0[j] = 0.0f; acc1[j] = 0.0f; }

  // depth-8 prefetch double buffer, 8 d's per group
  float2 xb[2][8];
  #pragma unroll
  for (int i = 0; i < 8; ++i) xb[0][i] = *(const float2*)(xp + (size_t)i * SS);

  float s2_0 = 0.0f, s2_1 = 0.0f;
  int buf = 0;
  for (int part = 0; part < 8; ++part) {
    float p0 = 0.0f, p1 = 0.0f;
    #pragma unroll
    for (int dd = 0; dd < 32; dd += 8) {
      const int d0 = part * 32 + dd;
      const int dn = (d0 + 8 < DD) ? (d0 + 8) : 0;  // clamp: harmless redundant prefetch
      #pragma unroll
      for (int i = 0; i < 8; ++i) xb[buf ^ 1][i] = *(const float2*)(xp + (size_t)(dn + i) * SS);
      #pragma unroll
      for (int g = 0; g < 2; ++g) {
        const float2 xa = xb[buf][4 * g + 0], xc2 = xb[buf][4 * g + 1],
                     xc3 = xb[buf][4 * g + 2], xc4 = xb[buf][4 * g + 3];
        // bit-exact chains: d-ascending per (k,s); norm singleton adds asc
        p0 += xa.x * xa.x; p0 += xc2.x * xc2.x; p0 += xc3.x * xc3.x; p0 += xc4.x * xc4.x;
        p1 += xa.y * xa.y; p1 += xc2.y * xc2.y; p1 += xc3.y * xc3.y; p1 += xc4.y * xc4.y;
        #pragma unroll
        for (int j = 0; j < 7; ++j) {
          const float4 tq = *(const float4*)(tvk[j] + d0 + 4 * g);  // wave-uniform -> s_load
          acc0[j] += xa.x * tq.x; acc0[j] += xc2.x * tq.y;
          acc0[j] += xc3.x * tq.z; acc0[j] += xc4.x * tq.w;
          acc1[j] += xa.y * tq.x; acc1[j] += xc2.y * tq.y;
          acc1[j] += xc3.y * tq.z; acc1[j] += xc4.y * tq.w;
        }
      }
      buf ^= 1;
    }
    s2_0 = (part == 0) ? p0 : (s2_0 + p0);
    s2_1 = (part == 0) ? p1 : (s2_1 + p1);
  }
  const float i0 = 1.0f / fmaxf(sqrtf(s2_0), 1e-12f);
  const float i1 = 1.0f / fmaxf(sqrtf(s2_1), 1e-12f);

  bool m = false;
  const size_t gs = (size_t)b * SS + s0 + 2 * lane;
  #pragma unroll
  for (int j = 0; j < 7; ++j) {
    if (kval[j]) {
      const int k = kb + 8 * j;
      float2 o;
      o.x = acc0[j] * i0;
      o.y = acc1[j] * i1;
      *(float2*)(tpn_t + (size_t)k * BS + gs) = o;
      m = m | (o.x > 0.3f) | (o.y > 0.3f);
    }
  }

  const int w = __any((int)m);
  if (lane == 0) wflag[wid] = w;
  __syncthreads();
  const int blockAny = (wflag[0] | wflag[1] | wflag[2] | wflag[3]) ? 1 : 0;

  if (t == 0) {
    // single packed atomic: low 16 bits = arrival count, high bits = flag sum.
    // Second arriver (old&0xFFFF==1) provably sees the first's flag in old>>16.
    const int old = atomicAdd(&tile_cnt[tile], (blockAny << 16) | 1);
    int dec = 0;
    if ((old & 0xFFFF) == 1) {     // second finisher: union is complete
      const int fl = (old >> 16) | blockAny;
      if (fl) {
        const int idx = atomicAdd(surv_cnt, 1);
        if (idx < MAXSURV) surv_list[idx] = tile;
      } else {
        atomicAdd(ae_acc, (float)TS);  // sum_s ||x_n||^2 = TS exactly
        dec = 1;
      }
    }
    decision = dec;
  }
  __syncthreads();
  if (decision) {
    float* ob = out_nn + ((size_t)b * SS + s0) * KK;
    for (int p2 = t; p2 < TS * KK; p2 += 256) ob[p2] = 0.0f;
  }
}

// Fused: blocks [0,800) = per-wave exact top-32 of 1024-elem chunks;
// blocks [800,864) = survivor tiles (nn from tpn_t, out_nn, r1, r2, pred, ae).
__global__ __launch_bounds__(256) void chunk_surv_kernel(
    const float* __restrict__ tpn_t, float* __restrict__ cand,
    const float* __restrict__ f_input, const float* __restrict__ rec1,
    const float* __restrict__ rec2, const int* __restrict__ surv_cnt,
    const int* __restrict__ surv_list, float* __restrict__ out_nn,
    float* __restrict__ predacc, float* __restrict__ ae_acc) {
  __shared__ __align__(16) float NNk[KK * 20];   // [k][s16] stride 20
  __shared__ __align__(16) float R1t[HH * 20];   // [h][s16] stride 20
  __shared__ float nprt[16][17];
  __shared__ float nrm[16], invn[16];
  __shared__ float pm[8 * DD];
  __shared__ float red4[4];

  const int t = threadIdx.x;
  const int lane = t & 63, wid = t >> 6;

  if (blockIdx.x < NCHBLK) {
    // ---------- chunk top-32 path (no LDS, no barriers) ----------
    const int gchunk = blockIdx.x * 4 + wid;
    const int k = gchunk >> 6;
    const int c = gchunk & (NCH - 1);
    const float* row = tpn_t + (size_t)k * BS + c * CHUNK;

    float v[16];
    unsigned key[16];
    #pragma unroll
    for (int j = 0; j < 16; ++j) {
      v[j] = row[lane + j * 64];
      key[j] = fkey(v[j]);
    }
    unsigned T = 0;
    for (int bit = 31; bit >= 0; --bit) {
      const unsigned ct = T | (1u << bit);
      int cnt = 0;
      #pragma unroll
      for (int j = 0; j < 16; ++j) cnt += (key[j] >= ct) ? 1 : 0;
      #pragma unroll
      for (int off = 1; off < 64; off <<= 1) cnt += __shfl_xor(cnt, off);
      if (cnt >= TOPK) T = ct;
    }
    int cg = 0;
    #pragma unroll
    for (int j = 0; j < 16; ++j) cg += (key[j] > T) ? 1 : 0;
    int incl = cg;
    #pragma unroll
    for (int off = 1; off < 64; off <<= 1) {
      int y = __shfl_up(incl, off);
      if (lane >= off) incl += y;
    }
    const int excl = incl - cg;
    const int total_gt = __shfl(incl, 63);

    float* cb = cand + (size_t)gchunk * TOPK;
    int pos = excl;
    #pragma unroll
    for (int j = 0; j < 16; ++j) {
      if (key[j] > T) cb[pos++] = v[j];
    }
    if (lane < TOPK - total_gt) cb[total_gt + lane] = keyval(T);
    return;
  }

  // ---------- survivor path ----------
  const int bid = blockIdx.x - NCHBLK;   // 0..63
  int cnt = *surv_cnt;
  if (cnt > MAXSURV) cnt = MAXSURV;
  const int ntask = NSUB * cnt;

  for (int task = bid; task < ntask; task += 64) {
    const int tile = surv_list[task / NSUB];
    const int q = task % NSUB;
    const int b = tile >> 2;
    const int s0 = (tile & 3) * TS + q * 16;
    const float* fb = f_input + (size_t)b * DD * SS;
    const size_t gs0 = (size_t)b * SS + s0;

    // stage tpn rows for these 16 s
    for (int p = t; p < KK * 16; p += 256) {
      const int k = p >> 4, ss = p & 15;
      NNk[k * 20 + ss] = tpn_t[(size_t)k * BS + gs0 + ss];
    }
    // cooperative norms: 16 d-parts x 16 s, 16 unrolled independent loads each
    {
      const int ss = t & 15, part = t >> 4;
      const float* xc = fb + (size_t)(part * 16) * SS + s0 + ss;
      float p = 0.0f;
      #pragma unroll
      for (int i = 0; i < 16; ++i) {
        const float v = xc[(size_t)i * SS];
        p += v * v;
      }
      nprt[part][ss] = p;
    }
    __syncthreads();
    if (t < 16) {
      float s2 = 0.0f;
      #pragma unroll
      for (int i = 0; i < 16; ++i) s2 += nprt[i][t];
      const float n = fmaxf(sqrtf(s2), 1e-12f);
      nrm[t] = n;
      invn[t] = 1.0f / n;
      float sm = 0.0f;
      for (int k = 0; k < KK; ++k) {
        const float tpn = NNk[k * 20 + t];
        sm += (tpn > 0.3f) ? tpn * n : 0.0f;
      }
      const float idv = 1.0f / (sm + 0.001f + 1e-8f);
      for (int k = 0; k < KK; ++k) {
        const float tpn = NNk[k * 20 + t];
        NNk[k * 20 + t] = (tpn > 0.3f) ? tpn * n * idv : 0.0f;
      }
    }
    __syncthreads();

    // write out_nn for these 16 s (scalar: out_nn only 4B-aligned)
    for (int p = t; p < 16 * KK; p += 256) {
      const int ss = p / KK, k = p - ss * KK;
      out_nn[(gs0 + ss) * KK + k] = NNk[k * 20 + ss];
    }

    // phase 4: r1[h=t][s] = relu(nn . rec1)
    {
      float a[16];
      #pragma unroll
      for (int i = 0; i < 16; ++i) a[i] = 0.0f;
      #pragma unroll 2
      for (int k = 0; k < KK; ++k) {
        const float r = rec1[k * HH + t];
        const float4* np = (const float4*)&NNk[k * 20];
        #pragma unroll
        for (int qq = 0; qq < 4; ++qq) {
          const float4 nv = np[qq];
          a[qq * 4 + 0] += nv.x * r;
          a[qq * 4 + 1] += nv.y * r;
          a[qq * 4 + 2] += nv.z * r;
          a[qq * 4 + 3] += nv.w * r;
        }
      }
      #pragma unroll
      for (int i = 0; i < 16; ++i) R1t[t * 20 + i] = fmaxf(a[i], 0.0f);
    }
    __syncthreads();

    // phase 5: r2 = r1 @ rec2; per thread 2s x 8d; h unrolled x8 with batch prefetch
    const int tx = t & 31, ty = t >> 5;
    const int d0 = tx * 8, sb = ty * 2;
    float c2[2][8];
    #pragma unroll
    for (int i = 0; i < 2; ++i)
      #pragma unroll
      for (int j = 0; j < 8; ++j) c2[i][j] = 0.0f;
    for (int h0 = 0; h0 < HH; h0 += 8) {
      float4 B0[8], B1[8];
      #pragma unroll
      for (int u = 0; u < 8; ++u) {
        B0[u] = *(const float4*)(rec2 + (h0 + u) * DD + d0);
        B1[u] = *(const float4*)(rec2 + (h0 + u) * DD + d0 + 4);
      }
      #pragma unroll
      for (int u = 0; u < 8; ++u) {
        const float2 a01 = *(const float2*)(&R1t[(h0 + u) * 20 + sb]);
        const float bv[8] = {B0[u].x, B0[u].y, B0[u].z, B0[u].w,
                             B1[u].x, B1[u].y, B1[u].z, B1[u].w};
        #pragma unroll
        for (int j = 0; j < 8; ++j) {
          c2[0][j] += a01.x * bv[j];
          c2[1][j] += a01.y * bv[j];
        }
      }
    }
    #pragma unroll
    for (int j = 0; j < 8; ++j) pm[ty * DD + d0 + j] = c2[0][j] + c2[1][j];
    __syncthreads();
    {
      float sum = 0.0f;
      #pragma unroll
      for (int r = 0; r < 8; ++r) sum += pm[r * DD + t];
      atomicAdd(&predacc[(size_t)b * DD + t], sum);
    }
    float e = 0.0f;
    #pragma unroll
    for (int j = 0; j < 8; ++j) {
      #pragma unroll
      for (int i = 0; i < 2; ++i) {
        const float x = fb[(size_t)(d0 + j) * SS + s0 + sb + i];
        const float diff = x * invn[sb + i] - c2[i][j];
        e += diff * diff;
      }
    }
    #pragma unroll
    for (int off = 1; off < 64; off <<= 1) e += __shfl_xor(e, off);
    if (lane == 0) red4[wid] = e;
    __syncthreads();
    if (t == 0) atomicAdd(ae_acc, red4[0] + red4[1] + red4[2] + red4[3]);
    __syncthreads();  // LDS reuse next task
  }
}

// Fused: blocks [0,128) pred head (+block0: far, out[256], ae);
// blocks [128,178) top-32 merge per concept; last merge finisher writes out[257].
__global__ __launch_bounds__(256) void merge_finalize_kernel(
    const float* __restrict__ cand, const float* __restrict__ predacc,
    const float* __restrict__ Wc, const float* __restrict__ bc,
    const float* __restrict__ ae_acc, float* __restrict__ sim_acc,
    unsigned* __restrict__ sim_done, const float* __restrict__ tvn,
    float* __restrict__ out) {
  __shared__ float r0[256], r1[256];
  const int blk = blockIdx.x;
  const int t = threadIdx.x;

  if (blk >= BB) {
    // ---- merge path: one wave, concept k ----
    if (t < 64) {
      const int k = blk - BB;
      const int lane = t;
      const float* row = cand + (size_t)k * (NCH * TOPK);
      float v[32];
      unsigned key[32];
      #pragma unroll
      for (int j = 0; j < 32; ++j) {
        v[j] = row[lane + j * 64];
        key[j] = fkey(v[j]);
      }
      unsigned T = 0;
      for (int bit = 31; bit >= 0; --bit) {
        const unsigned ct = T | (1u << bit);
        int cnt = 0;
        #pragma unroll
        for (int j = 0; j < 32; ++j) cnt += (key[j] >= ct) ? 1 : 0;
        #pragma unroll
        for (int off = 1; off < 64; off <<= 1) cnt += __shfl_xor(cnt, off);
        if (cnt >= TOPK) T = ct;
      }
      float s = 0.0f;
      int cgt = 0;
      #pragma unroll
      for (int j = 0; j < 32; ++j) {
        if (key[j] > T) { s += v[j]; cgt++; }
      }
      #pragma unroll
      for (int off = 1; off < 64; off <<= 1) {
        s += __shfl_xor(s, off);
        cgt += __shfl_xor(cgt, off);
      }
      if (lane == 0) {
        atomicAdd(sim_acc, s + (float)(TOPK - cgt) * keyval(T));
        __threadfence();
        const unsigned c = atomicAdd(sim_done, 1u);
        if (c == KK - 1) {               // last finisher: total is complete
          __threadfence();
          const float tot = atomicAdd(sim_acc, 0.0f);
          out[257] = -tot * (1.0f / (float)(KK * TOPK));
        }
      }
    }
    return;
  }

  // ---- finalize path: pred head for b = blk ----
  const float s = predacc[(size_t)blk * DD + t];
  r0[t] = s * Wc[t * 2 + 0];
  r1[t] = s * Wc[t * 2 + 1];
  __syncthreads();
  for (int off = 128; off > 0; off >>= 1) {
    if (t < off) { r0[t] += r0[t + off]; r1[t] += r1[t + off]; }
    __syncthreads();
  }
  if (t == 0) {
    out[blk * 2 + 0] = r0[0] * (1.0f / (float)SS) + bc[0];
    out[blk * 2 + 1] = r1[0] * (1.0f / (float)SS) + bc[1];
    if (blk == 0) {
      out[256] = 0.0f;
      out[OUT_AE_IDX] = (*ae_acc) * (1.0f / ((float)BB * (float)SS * (float)DD));
    }
  }
  if (blk == 0) {
    // concept_far: sum(G) = sum_d (rowsum_d)^2 since G = tvn^T tvn
    __syncthreads();
    float rs = 0.0f;
    for (int k = 0; k < KK; ++k) rs += tvn[t * KK + k];
    r0[t] = rs * rs;
    __syncthreads();
    for (int off = 128; off > 0; off >>= 1) {
      if (t < off) r0[t] += r0[t + off];
      __syncthreads();
    }
    if (t == 0) out[258] = (r0[0] - (float)KK) / ((float)KK * (float)KK);
  }
}

extern "C" void kernel_launch(void* const* d_in, const int* in_sizes, int n_in,
                              void* d_out, int out_size, void* d_ws, size_t ws_size,
                              hipStream_t stream) {
  (void)in_sizes; (void)n_in; (void)out_size; (void)ws_size;
  const float* f_input = (const float*)d_in[0];
  const float* tv = (const float*)d_in[2];
  const float* rec1 = (const float*)d_in[3];
  const float* rec2 = (const float*)d_in[4];
  const float* Wc = (const float*)d_in[5];
  const float* bc = (const float*)d_in[6];

  float* out = (float*)d_out;
  float* ws = (float*)d_ws;
  float* tvn = ws + TVN_OFF;
  float* tvnT = ws + TVNT_OFF;
  float* tpn_t = ws + TPNT_OFF;
  float* predacc = ws + PREDACC_OFF;
  float* ae_acc = ws + AE_OFF;
  float* sim_acc = ws + SIM_OFF;
  int* surv_cnt = (int*)(ws + CNT_OFF);
  unsigned* sim_done = (unsigned*)(ws + SIMD_OFF);
  int* tile_flag = (int*)(ws + TFLAG_OFF);
  int* tile_cnt = (int*)(ws + TCNT_OFF);
  int* surv_list = (int*)(ws + LIST_OFF);
  float* cand = ws + CAND_OFF;

  tvn_kernel<<<KK, 256, 0, stream>>>(tv, tvn, tvnT, predacc);
  main_kernel<<<NBLK, 256, 0, stream>>>(f_input, tvnT, out + OUT_NN_OFF, tpn_t,
                                        ae_acc, surv_cnt, surv_list,
                                        tile_flag, tile_cnt);
  chunk_surv_kernel<<<NCHBLK + 64, 256, 0, stream>>>(
      tpn_t, cand, f_input, rec1, rec2, surv_cnt, surv_list,
      out + OUT_NN_OFF, predacc, ae_acc);
  merge_finalize_kernel<<<BB + KK, 256, 0, stream>>>(
      cand, predacc, Wc, bc, ae_acc, sim_acc, sim_done, tvn, out);
}